// Round 2
// baseline (1718.196 us; speedup 1.0000x reference)
//
#include <hip/hip_runtime.h>
#include <math.h>

#define NN 20000
#define NE 160000
#define TT 3
#define DD 128
#define NTOT 80000   // (TT+1)*NN
#define N3 60000     // TT*NN

__device__ __forceinline__ float waveReduceSum(float v) {
#pragma unroll
  for (int off = 32; off >= 1; off >>= 1)
    v += __shfl_xor(v, off, 64);
  return v;
}

__device__ __forceinline__ void atomAddF(float* p, float v) {
  unsafeAtomicAdd(p, v);
}

// ---------------------------------------------------------------------------
// copy features into all_features rows [0, NN)
__global__ __launch_bounds__(256) void k_copy_feat(const float* __restrict__ src,
                                                   float* __restrict__ dst, int n4) {
  int i = blockIdx.x * 256 + threadIdx.x;
  if (i < n4) ((float4*)dst)[i] = ((const float4*)src)[i];
}

// ---------------------------------------------------------------------------
// Generic [M,128] @ [128,128] GEMM. W (optionally transposed) staged in LDS,
// X tile staged transposed in LDS. 64 rows x 128 cols per block, 8x4 per thread.
template <int RELU_IN, int TRANS_W>
__global__ __launch_bounds__(256) void gemm128(const float* __restrict__ X,
                                               const float* __restrict__ W,
                                               const float* __restrict__ bias,
                                               float* __restrict__ out, int M,
                                               float scale, int wStride, int bStride,
                                               long oStride) {
  __shared__ float Ws[64 * 132];
  __shared__ float Xs[64 * 68];
  const int tid = threadIdx.x;
  const int rbase = blockIdx.x * 64;
  W += (long)blockIdx.y * wStride;
  if (bias) bias += (long)blockIdx.y * bStride;
  out += (long)blockIdx.y * oStride;

  const int c0 = (tid & 31) * 4;
  const int r0 = (tid >> 5) * 8;
  float acc[8][4];
#pragma unroll
  for (int i = 0; i < 8; ++i)
#pragma unroll
    for (int j = 0; j < 4; ++j) acc[i][j] = 0.f;

  for (int kt = 0; kt < 128; kt += 64) {
    __syncthreads();
    if (!TRANS_W) {
      for (int i = tid; i < 64 * 128; i += 256) {
        int kl = i >> 7, c = i & 127;
        Ws[kl * 132 + c] = W[(kt + kl) * 128 + c];
      }
    } else {
      for (int i = tid; i < 64 * 128; i += 256) {
        int kl = i & 63, c = i >> 6;
        Ws[kl * 132 + c] = W[c * 128 + kt + kl];
      }
    }
    for (int i = tid; i < 64 * 64; i += 256) {
      int kl = i & 63, row = i >> 6;
      int gr = rbase + row;
      float x = (gr < M) ? X[(long)gr * 128 + kt + kl] : 0.f;
      if (RELU_IN) x = fmaxf(x, 0.f);
      Xs[kl * 68 + row] = x;
    }
    __syncthreads();
#pragma unroll 8
    for (int kl = 0; kl < 64; ++kl) {
      const float4 b4 = *(const float4*)&Ws[kl * 132 + c0];
      const float4 a04 = *(const float4*)&Xs[kl * 68 + r0];
      const float4 a14 = *(const float4*)&Xs[kl * 68 + r0 + 4];
      float a[8] = {a04.x, a04.y, a04.z, a04.w, a14.x, a14.y, a14.z, a14.w};
      float b[4] = {b4.x, b4.y, b4.z, b4.w};
#pragma unroll
      for (int i = 0; i < 8; ++i)
#pragma unroll
        for (int j = 0; j < 4; ++j) acc[i][j] = fmaf(a[i], b[j], acc[i][j]);
    }
  }
  float bb0 = 0.f, bb1 = 0.f, bb2 = 0.f, bb3 = 0.f;
  if (bias) {
    bb0 = bias[c0];
    bb1 = bias[c0 + 1];
    bb2 = bias[c0 + 2];
    bb3 = bias[c0 + 3];
  }
#pragma unroll
  for (int i = 0; i < 8; ++i) {
    int gr = rbase + r0 + i;
    if (gr < M) {
      float4 v;
      v.x = acc[i][0] * scale + bb0;
      v.y = acc[i][1] * scale + bb1;
      v.z = acc[i][2] * scale + bb2;
      v.w = acc[i][3] * scale + bb3;
      *(float4*)&out[(long)gr * 128 + c0] = v;
    }
  }
}

// ---------------------------------------------------------------------------
// row norms: first NN waves -> ||features[j]||, next NN -> ||transformed0[j]||
__global__ __launch_bounds__(256) void k_norms(const float* __restrict__ feat,
                                               const float* __restrict__ A,
                                               float* __restrict__ nf,
                                               float* __restrict__ nt0) {
  int w = blockIdx.x * 4 + (threadIdx.x >> 6);
  int lane = threadIdx.x & 63;
  if (w >= 2 * NN) return;
  const float* p = (w < NN) ? (feat + (long)w * 128) : (A + (long)(NN + (w - NN)) * 128);
  float v0 = p[lane], v1 = p[lane + 64];
  float s = waveReduceSum(v0 * v0 + v1 * v1);
  if (lane == 0) {
    float r = sqrtf(s);
    if (w < NN) nf[w] = r;
    else nt0[w - NN] = r;
  }
}

__global__ __launch_bounds__(256) void k_deg_init(float* __restrict__ deg) {
  int v = blockIdx.x * 256 + threadIdx.x;
  if (v < NTOT) deg[v] = (v < N3) ? 2.f : 1.f;
}

// cosine-sim replica selection; one wave per edge. Also deg atomics for the
// two data-dependent edge families.
__global__ __launch_bounds__(256) void k_sim(const int* __restrict__ ei,
                                             const float* __restrict__ feat,
                                             const float* __restrict__ A,
                                             const float* __restrict__ nf,
                                             const float* __restrict__ nt0,
                                             int* __restrict__ bn,
                                             float* __restrict__ deg) {
  int e = blockIdx.x * 4 + (threadIdx.x >> 6);
  int lane = threadIdx.x & 63;
  if (e >= NE) return;
  int s = ei[e];
  const float* fp = feat + (long)s * 128;
  float a0 = fp[lane], a1 = fp[lane + 64];
  float na = nf[s];
  float bv = 0.f;
  int bk = 0;
#pragma unroll
  for (int k = 0; k < 3; ++k) {
    int j = 3 * e + k;
    if (j >= NE) j -= NE;
    if (j >= NE) j -= NE;
    int d = ei[NE + j];
    const float* bp = A + (long)(NN + d) * 128;
    float dot = waveReduceSum(a0 * bp[lane] + a1 * bp[lane + 64]);
    float sim = dot / fmaxf(na * nt0[d], 1e-8f);
    if (k == 0 || sim > bv) {
      bv = sim;
      bk = k;
    }
  }
  if (lane == 0) {
    int d0 = ei[NE + e];
    int b2 = d0 + bk * NN;
    bn[e] = b2;
    atomAddF(&deg[d0], 1.f);
    atomAddF(&deg[b2], 1.f);
  }
}

__global__ __launch_bounds__(256) void k_dinv(float* __restrict__ deg) {
  int v = blockIdx.x * 256 + threadIdx.x;
  if (v < NTOT) deg[v] = 1.f / sqrtf(deg[v]);
}

// structured GCN contributions: self-loop + extra edges, plus bias
__global__ __launch_bounds__(256) void k_gcn_init(const float* __restrict__ xw,
                                                  const float* __restrict__ dinv,
                                                  const float* __restrict__ bias,
                                                  float* __restrict__ out) {
  int v = blockIdx.x * 2 + (threadIdx.x >> 7);
  int c = threadIdx.x & 127;
  if (v >= NTOT) return;
  float dv = dinv[v];
  float acc = bias[c] + dv * dv * xw[(long)v * 128 + c];
  if (v < NN) {
    acc += dv * dv * xw[(long)v * 128 + c];  // extra edge (j, j)
  } else if (v < N3) {
    int j = (v < 2 * NN) ? (v - NN) : (v - 2 * NN);
    acc += dinv[j] * dv * xw[(long)j * 128 + c];  // extra edge (j, i*NN + j)
  }
  out[(long)v * 128 + c] = acc;
}

// unstructured edges: (src, dst) and (src, best_node); one wave per edge
__global__ __launch_bounds__(256) void k_scatter(const int* __restrict__ ei,
                                                 const int* __restrict__ bn,
                                                 const float* __restrict__ xw,
                                                 const float* __restrict__ dinv,
                                                 float* __restrict__ out) {
  int e = blockIdx.x * 4 + (threadIdx.x >> 6);
  int lane = threadIdx.x & 63;
  if (e >= NE) return;
  int s = ei[e], d1 = ei[NE + e], d2 = bn[e];
  float ds = dinv[s];
  float w1 = ds * dinv[d1], w2 = ds * dinv[d2];
  const float* xr = xw + (long)s * 128;
  float x0 = xr[lane], x1 = xr[lane + 64];
  atomAddF(&out[(long)d1 * 128 + lane], w1 * x0);
  atomAddF(&out[(long)d1 * 128 + lane + 64], w1 * x1);
  atomAddF(&out[(long)d2 * 128 + lane], w2 * x0);
  atomAddF(&out[(long)d2 * 128 + lane + 64], w2 * x1);
}

// per-row argmax (first max) over 128 logits; 2 rows per block
__global__ __launch_bounds__(256) void k_argmax(const float* __restrict__ logits,
                                                int* __restrict__ cls) {
  __shared__ float sv[2][128];
  __shared__ int si[2][128];
  int half = threadIdx.x >> 7;
  int c = threadIdx.x & 127;
  long row = (long)blockIdx.x * 2 + half;
  sv[half][c] = logits[row * 128 + c];
  si[half][c] = c;
  __syncthreads();
  for (int off = 64; off >= 1; off >>= 1) {
    if (c < off) {
      float v1 = sv[half][c], v2 = sv[half][c + off];
      int i1 = si[half][c], i2 = si[half][c + off];
      if (v2 > v1 || (v2 == v1 && i2 < i1)) {
        sv[half][c] = v2;
        si[half][c] = i2;
      }
    }
    __syncthreads();
  }
  if (c == 0) cls[row] = si[half][0];
}

__global__ __launch_bounds__(256) void k_zero_small(float* __restrict__ hyper,
                                                    int* __restrict__ hist) {
  int i = blockIdx.x * 256 + threadIdx.x;
  if (i < 128 * 128) hyper[i] = 0.f;
  if (i < 640) hist[i] = 0;
}

// vote histogram: hist[c][m] = #nodes whose count for class c is exactly m
__global__ __launch_bounds__(256) void k_hist(const int* __restrict__ cls,
                                              int* __restrict__ hist) {
  int j = blockIdx.x * 256 + threadIdx.x;
  if (j >= NN) return;
  int cc[4] = {cls[j], cls[NN + j], cls[2 * NN + j], cls[3 * NN + j]};
#pragma unroll
  for (int i = 0; i < 4; ++i) {
    bool first = true;
    int m = 0;
#pragma unroll
    for (int k = 0; k < 4; ++k) {
      if (cc[k] == cc[i]) {
        if (k < i) first = false;
        m++;
      }
    }
    if (first) atomicAdd(&hist[cc[i] * 5 + m], 1);
  }
}

// per-class softmax table over count values 0..4
__global__ void k_table(const int* __restrict__ hist, float* __restrict__ table) {
  int c = threadIdx.x;
  if (c >= 128) return;
  int cnt[5];
  int tot = 0;
  for (int v = 1; v <= 4; ++v) {
    cnt[v] = hist[c * 5 + v];
    tot += cnt[v];
  }
  cnt[0] = NN - tot;
  int m = 0;
  for (int v = 0; v <= 4; ++v)
    if (cnt[v] > 0) m = v;
  float ex[5];
  float denom = 0.f;
  for (int v = 0; v <= 4; ++v) {
    ex[v] = expf((float)(v - m));
    denom += (float)cnt[v] * ex[v];
  }
  for (int v = 0; v <= 4; ++v) table[c * 5 + v] = ex[v] / denom;
}

__global__ __launch_bounds__(256) void k_hwrite(const int* __restrict__ cls,
                                                const float* __restrict__ table,
                                                float* __restrict__ H) {
  int j = blockIdx.x * 2 + (threadIdx.x >> 7);
  int c = threadIdx.x & 127;
  if (j >= NN) return;
  int c0 = cls[j], c1 = cls[NN + j], c2 = cls[2 * NN + j], c3 = cls[3 * NN + j];
  int cnt = (c == c0) + (c == c1) + (c == c2) + (c == c3);
  H[(long)j * 128 + c] = table[c * 5 + cnt];
}

// hyper[c][d] = sum over nodes voting for class c of af2[j][d]
#define HCHUNK 2500
__global__ __launch_bounds__(128) void k_hyper(const int* __restrict__ cls,
                                               const float* __restrict__ af2,
                                               float* __restrict__ hyper) {
  int c = blockIdx.x & 127;
  int chunk = blockIdx.x >> 7;
  int d = threadIdx.x;
  int j0 = chunk * HCHUNK, j1 = j0 + HCHUNK;
  float acc = 0.f;
  for (int j = j0; j < j1; ++j) {
    int c0 = cls[j], c1 = cls[NN + j], c2 = cls[2 * NN + j], c3 = cls[3 * NN + j];
    if (c == c0 || c == c1 || c == c2 || c == c3) acc += af2[(long)j * 128 + d];
  }
  atomAddF(&hyper[c * 128 + d], acc);
}

// ---------------------------------------------------------------------------
extern "C" void kernel_launch(void* const* d_in, const int* in_sizes, int n_in,
                              void* d_out, int out_size, void* d_ws, size_t ws_size,
                              hipStream_t stream) {
  (void)in_sizes;
  (void)n_in;
  (void)out_size;
  (void)ws_size;
  const int* ei = (const int*)d_in[0];
  const float* feat = (const float*)d_in[1];
  const float* lin_W = (const float*)d_in[2];
  const float* lin_b = (const float*)d_in[3];
  const float* g1W = (const float*)d_in[4];
  const float* g1b = (const float*)d_in[5];
  const float* g2W = (const float*)d_in[6];
  const float* g2b = (const float*)d_in[7];
  const float* l1W = (const float*)d_in[8];
  const float* l1b = (const float*)d_in[9];

  float* out = (float*)d_out;
  float* H = out;
  float* hyper = out + (size_t)NN * 128;
  float* dots = hyper + 128 * 128;

  float* ws = (float*)d_ws;
  float* A = ws;                          // all_features [(T+1)*NN, 128]
  float* Cb = A + (size_t)NTOT * 128;     // h1 / af2 buffer
  float* Bb = dots;                       // xw / logits buffer aliased onto dots
                                          // (dots is written only by the final
                                          //  GEMM, after the last read of Bb)
  float* dinv = Cb + (size_t)NTOT * 128;  // deg -> dinv [NTOT]
  float* nf = dinv + NTOT;                // feature norms [NN]
  float* nt0 = nf + NN;                   // transformed0 norms [NN]
  int* bn = (int*)(nt0 + NN);             // best_nodes [NE]
  int* cls = bn + NE;                     // classes [NTOT]
  int* hist = cls + NTOT;                 // [128*5]
  float* table = (float*)(hist + 640);    // [128*5]

  const float kScale = 0.08838834764831843f;  // 128^-0.5

  // 1. all_features rows [0,NN) = features
  k_copy_feat<<<(NN * 128 / 4 + 255) / 256, 256, 0, stream>>>(feat, A, NN * 128 / 4);
  // 2. transformed: per-replica linears -> rows [NN, 4*NN)
  gemm128<0, 0><<<dim3(313, 3), 256, 0, stream>>>(feat, lin_W, lin_b, A + (size_t)NN * 128,
                                                  NN, 1.f, 128 * 128, 128,
                                                  (long)NN * 128);
  // 3. row norms
  k_norms<<<10000, 256, 0, stream>>>(feat, A, nf, nt0);
  // 4. degree init (self loops + structured extra edges)
  k_deg_init<<<(NTOT + 255) / 256, 256, 0, stream>>>(dinv);
  // 5. cosine-sim replica pick + degree atomics
  k_sim<<<NE / 4, 256, 0, stream>>>(ei, feat, A, nf, nt0, bn, dinv);
  // 6. deg -> 1/sqrt(deg)
  k_dinv<<<(NTOT + 255) / 256, 256, 0, stream>>>(dinv);
  // 7. GCN1: xw1 = relu(all_features) @ W1
  gemm128<1, 0><<<dim3(NTOT / 64, 1), 256, 0, stream>>>(A, g1W, nullptr, Bb, NTOT, 1.f,
                                                        0, 0, 0);
  // 8-9. structured init + edge scatter -> h1 (pre-relu) in Cb
  k_gcn_init<<<NTOT / 2, 256, 0, stream>>>(Bb, dinv, g1b, Cb);
  k_scatter<<<NE / 4, 256, 0, stream>>>(ei, bn, Bb, dinv, Cb);
  // 10. GCN2: xw2 = relu(h1) @ W2
  gemm128<1, 0><<<dim3(NTOT / 64, 1), 256, 0, stream>>>(Cb, g2W, nullptr, Bb, NTOT, 1.f,
                                                        0, 0, 0);
  // 11-12. structured init + edge scatter -> af2 in Cb
  k_gcn_init<<<NTOT / 2, 256, 0, stream>>>(Bb, dinv, g2b, Cb);
  k_scatter<<<NE / 4, 256, 0, stream>>>(ei, bn, Bb, dinv, Cb);
  // 13. logits = relu(af2) @ lin1_W + lin1_b -> Bb
  gemm128<1, 0><<<dim3(NTOT / 64, 1), 256, 0, stream>>>(Cb, l1W, l1b, Bb, NTOT, 1.f, 0,
                                                        0, 0);
  // 14. per-row argmax -> classes
  k_argmax<<<NTOT / 2, 256, 0, stream>>>(Bb, cls);
  // 15. zero hyper + hist
  k_zero_small<<<64, 256, 0, stream>>>(hyper, hist);
  // 16-17. vote histogram -> per-class softmax table
  k_hist<<<(NN + 255) / 256, 256, 0, stream>>>(cls, hist);
  k_table<<<1, 128, 0, stream>>>(hist, table);
  // 18. H output (softmax over nodes, via count table)
  k_hwrite<<<NN / 2, 256, 0, stream>>>(cls, table, H);
  // 19. hyperedge features
  k_hyper<<<1024, 128, 0, stream>>>(cls, Cb, hyper);
  // 20. dots = all_features @ hyper^T * scale
  gemm128<0, 1><<<dim3(NTOT / 64, 1), 256, 0, stream>>>(A, hyper, nullptr, dots, NTOT,
                                                        kScale, 0, 0, 0);
}

// Round 3
// 909.029 us; speedup vs baseline: 1.8901x; 1.8901x over previous
//
#include <hip/hip_runtime.h>
#include <math.h>

#define NN 20000
#define NE 160000
#define TT 3
#define DD 128
#define NTOT 80000   // (TT+1)*NN
#define N3 60000     // TT*NN

__device__ __forceinline__ float waveReduceSum(float v) {
#pragma unroll
  for (int off = 32; off >= 1; off >>= 1)
    v += __shfl_xor(v, off, 64);
  return v;
}

__device__ __forceinline__ void atomAddF(float* p, float v) {
  unsafeAtomicAdd(p, v);
}

// ---------------------------------------------------------------------------
// copy features into all_features rows [0, NN)
__global__ __launch_bounds__(256) void k_copy_feat(const float* __restrict__ src,
                                                   float* __restrict__ dst, int n4) {
  int i = blockIdx.x * 256 + threadIdx.x;
  if (i < n4) ((float4*)dst)[i] = ((const float4*)src)[i];
}

// ---------------------------------------------------------------------------
// Generic [M,128] @ [128,128] GEMM. W (optionally transposed) staged in LDS,
// X tile staged transposed in LDS. 64 rows x 128 cols per block, 8x4 per thread.
template <int RELU_IN, int TRANS_W>
__global__ __launch_bounds__(256) void gemm128(const float* __restrict__ X,
                                               const float* __restrict__ W,
                                               const float* __restrict__ bias,
                                               float* __restrict__ out, int M,
                                               float scale, int wStride, int bStride,
                                               long oStride) {
  __shared__ float Ws[64 * 132];
  __shared__ float Xs[64 * 68];
  const int tid = threadIdx.x;
  const int rbase = blockIdx.x * 64;
  W += (long)blockIdx.y * wStride;
  if (bias) bias += (long)blockIdx.y * bStride;
  out += (long)blockIdx.y * oStride;

  const int c0 = (tid & 31) * 4;
  const int r0 = (tid >> 5) * 8;
  float acc[8][4];
#pragma unroll
  for (int i = 0; i < 8; ++i)
#pragma unroll
    for (int j = 0; j < 4; ++j) acc[i][j] = 0.f;

  for (int kt = 0; kt < 128; kt += 64) {
    __syncthreads();
    if (!TRANS_W) {
      for (int i = tid; i < 64 * 128; i += 256) {
        int kl = i >> 7, c = i & 127;
        Ws[kl * 132 + c] = W[(kt + kl) * 128 + c];
      }
    } else {
      for (int i = tid; i < 64 * 128; i += 256) {
        int kl = i & 63, c = i >> 6;
        Ws[kl * 132 + c] = W[c * 128 + kt + kl];
      }
    }
    for (int i = tid; i < 64 * 64; i += 256) {
      int kl = i & 63, row = i >> 6;
      int gr = rbase + row;
      float x = (gr < M) ? X[(long)gr * 128 + kt + kl] : 0.f;
      if (RELU_IN) x = fmaxf(x, 0.f);
      Xs[kl * 68 + row] = x;
    }
    __syncthreads();
#pragma unroll 8
    for (int kl = 0; kl < 64; ++kl) {
      const float4 b4 = *(const float4*)&Ws[kl * 132 + c0];
      const float4 a04 = *(const float4*)&Xs[kl * 68 + r0];
      const float4 a14 = *(const float4*)&Xs[kl * 68 + r0 + 4];
      float a[8] = {a04.x, a04.y, a04.z, a04.w, a14.x, a14.y, a14.z, a14.w};
      float b[4] = {b4.x, b4.y, b4.z, b4.w};
#pragma unroll
      for (int i = 0; i < 8; ++i)
#pragma unroll
        for (int j = 0; j < 4; ++j) acc[i][j] = fmaf(a[i], b[j], acc[i][j]);
    }
  }
  float bb0 = 0.f, bb1 = 0.f, bb2 = 0.f, bb3 = 0.f;
  if (bias) {
    bb0 = bias[c0];
    bb1 = bias[c0 + 1];
    bb2 = bias[c0 + 2];
    bb3 = bias[c0 + 3];
  }
#pragma unroll
  for (int i = 0; i < 8; ++i) {
    int gr = rbase + r0 + i;
    if (gr < M) {
      float4 v;
      v.x = acc[i][0] * scale + bb0;
      v.y = acc[i][1] * scale + bb1;
      v.z = acc[i][2] * scale + bb2;
      v.w = acc[i][3] * scale + bb3;
      *(float4*)&out[(long)gr * 128 + c0] = v;
    }
  }
}

// ---------------------------------------------------------------------------
// row norms: first NN waves -> ||features[j]||, next NN -> ||transformed0[j]||
__global__ __launch_bounds__(256) void k_norms(const float* __restrict__ feat,
                                               const float* __restrict__ A,
                                               float* __restrict__ nf,
                                               float* __restrict__ nt0) {
  int w = blockIdx.x * 4 + (threadIdx.x >> 6);
  int lane = threadIdx.x & 63;
  if (w >= 2 * NN) return;
  const float* p = (w < NN) ? (feat + (long)w * 128) : (A + (long)(NN + (w - NN)) * 128);
  float v0 = p[lane], v1 = p[lane + 64];
  float s = waveReduceSum(v0 * v0 + v1 * v1);
  if (lane == 0) {
    float r = sqrtf(s);
    if (w < NN) nf[w] = r;
    else nt0[w - NN] = r;
  }
}

__global__ __launch_bounds__(256) void k_deg_init(float* __restrict__ deg) {
  int v = blockIdx.x * 256 + threadIdx.x;
  if (v < NTOT) deg[v] = (v < N3) ? 2.f : 1.f;
}

// cosine-sim replica selection; one wave per edge. Also deg atomics for the
// two data-dependent edge families.
__global__ __launch_bounds__(256) void k_sim(const int* __restrict__ ei,
                                             const float* __restrict__ feat,
                                             const float* __restrict__ A,
                                             const float* __restrict__ nf,
                                             const float* __restrict__ nt0,
                                             int* __restrict__ bn,
                                             float* __restrict__ deg) {
  int e = blockIdx.x * 4 + (threadIdx.x >> 6);
  int lane = threadIdx.x & 63;
  if (e >= NE) return;
  int s = ei[e];
  const float* fp = feat + (long)s * 128;
  float a0 = fp[lane], a1 = fp[lane + 64];
  float na = nf[s];
  float bv = 0.f;
  int bk = 0;
#pragma unroll
  for (int k = 0; k < 3; ++k) {
    int j = 3 * e + k;
    if (j >= NE) j -= NE;
    if (j >= NE) j -= NE;
    int d = ei[NE + j];
    const float* bp = A + (long)(NN + d) * 128;
    float dot = waveReduceSum(a0 * bp[lane] + a1 * bp[lane + 64]);
    float sim = dot / fmaxf(na * nt0[d], 1e-8f);
    if (k == 0 || sim > bv) {
      bv = sim;
      bk = k;
    }
  }
  if (lane == 0) {
    int d0 = ei[NE + e];
    int b2 = d0 + bk * NN;
    bn[e] = b2;
    atomAddF(&deg[d0], 1.f);
    atomAddF(&deg[b2], 1.f);
  }
}

__global__ __launch_bounds__(256) void k_dinv(float* __restrict__ deg) {
  int v = blockIdx.x * 256 + threadIdx.x;
  if (v < NTOT) deg[v] = 1.f / sqrtf(deg[v]);
}

// structured GCN contributions: self-loop + extra edges, plus bias
__global__ __launch_bounds__(256) void k_gcn_init(const float* __restrict__ xw,
                                                  const float* __restrict__ dinv,
                                                  const float* __restrict__ bias,
                                                  float* __restrict__ out) {
  int v = blockIdx.x * 2 + (threadIdx.x >> 7);
  int c = threadIdx.x & 127;
  if (v >= NTOT) return;
  float dv = dinv[v];
  float acc = bias[c] + dv * dv * xw[(long)v * 128 + c];
  if (v < NN) {
    acc += dv * dv * xw[(long)v * 128 + c];  // extra edge (j, j)
  } else if (v < N3) {
    int j = (v < 2 * NN) ? (v - NN) : (v - 2 * NN);
    acc += dinv[j] * dv * xw[(long)j * 128 + c];  // extra edge (j, i*NN + j)
  }
  out[(long)v * 128 + c] = acc;
}

// unstructured edges: (src, dst) and (src, best_node); one wave per edge
__global__ __launch_bounds__(256) void k_scatter(const int* __restrict__ ei,
                                                 const int* __restrict__ bn,
                                                 const float* __restrict__ xw,
                                                 const float* __restrict__ dinv,
                                                 float* __restrict__ out) {
  int e = blockIdx.x * 4 + (threadIdx.x >> 6);
  int lane = threadIdx.x & 63;
  if (e >= NE) return;
  int s = ei[e], d1 = ei[NE + e], d2 = bn[e];
  float ds = dinv[s];
  float w1 = ds * dinv[d1], w2 = ds * dinv[d2];
  const float* xr = xw + (long)s * 128;
  float x0 = xr[lane], x1 = xr[lane + 64];
  atomAddF(&out[(long)d1 * 128 + lane], w1 * x0);
  atomAddF(&out[(long)d1 * 128 + lane + 64], w1 * x1);
  atomAddF(&out[(long)d2 * 128 + lane], w2 * x0);
  atomAddF(&out[(long)d2 * 128 + lane + 64], w2 * x1);
}

// per-row argmax (first max) over 128 logits; 2 rows per block
__global__ __launch_bounds__(256) void k_argmax(const float* __restrict__ logits,
                                                int* __restrict__ cls) {
  __shared__ float sv[2][128];
  __shared__ int si[2][128];
  int half = threadIdx.x >> 7;
  int c = threadIdx.x & 127;
  long row = (long)blockIdx.x * 2 + half;
  sv[half][c] = logits[row * 128 + c];
  si[half][c] = c;
  __syncthreads();
  for (int off = 64; off >= 1; off >>= 1) {
    if (c < off) {
      float v1 = sv[half][c], v2 = sv[half][c + off];
      int i1 = si[half][c], i2 = si[half][c + off];
      if (v2 > v1 || (v2 == v1 && i2 < i1)) {
        sv[half][c] = v2;
        si[half][c] = i2;
      }
    }
    __syncthreads();
  }
  if (c == 0) cls[row] = si[half][0];
}

__global__ __launch_bounds__(256) void k_zero_small(float* __restrict__ hyper,
                                                    int* __restrict__ hist) {
  int i = blockIdx.x * 256 + threadIdx.x;
  if (i < 128 * 128) hyper[i] = 0.f;
  if (i < 640) hist[i] = 0;
}

// vote histogram: hist[c][m] = #nodes whose count for class c is exactly m
__global__ __launch_bounds__(256) void k_hist(const int* __restrict__ cls,
                                              int* __restrict__ hist) {
  int j = blockIdx.x * 256 + threadIdx.x;
  if (j >= NN) return;
  int cc[4] = {cls[j], cls[NN + j], cls[2 * NN + j], cls[3 * NN + j]};
#pragma unroll
  for (int i = 0; i < 4; ++i) {
    bool first = true;
    int m = 0;
#pragma unroll
    for (int k = 0; k < 4; ++k) {
      if (cc[k] == cc[i]) {
        if (k < i) first = false;
        m++;
      }
    }
    if (first) atomicAdd(&hist[cc[i] * 5 + m], 1);
  }
}

// per-class softmax table over count values 0..4
__global__ void k_table(const int* __restrict__ hist, float* __restrict__ table) {
  int c = threadIdx.x;
  if (c >= 128) return;
  int cnt[5];
  int tot = 0;
  for (int v = 1; v <= 4; ++v) {
    cnt[v] = hist[c * 5 + v];
    tot += cnt[v];
  }
  cnt[0] = NN - tot;
  int m = 0;
  for (int v = 0; v <= 4; ++v)
    if (cnt[v] > 0) m = v;
  float ex[5];
  float denom = 0.f;
  for (int v = 0; v <= 4; ++v) {
    ex[v] = expf((float)(v - m));
    denom += (float)cnt[v] * ex[v];
  }
  for (int v = 0; v <= 4; ++v) table[c * 5 + v] = ex[v] / denom;
}

__global__ __launch_bounds__(256) void k_hwrite(const int* __restrict__ cls,
                                                const float* __restrict__ table,
                                                float* __restrict__ H) {
  int j = blockIdx.x * 2 + (threadIdx.x >> 7);
  int c = threadIdx.x & 127;
  if (j >= NN) return;
  int c0 = cls[j], c1 = cls[NN + j], c2 = cls[2 * NN + j], c3 = cls[3 * NN + j];
  int cnt = (c == c0) + (c == c1) + (c == c2) + (c == c3);
  H[(long)j * 128 + c] = table[c * 5 + cnt];
}

// ---------------------------------------------------------------------------
// hyper[c][d] = sum over nodes voting for class c of af2[j][d].
// LDS-accumulated: 250 blocks x 80 nodes; per node, 256 threads cover
// 2 class-slots x 128 dims each, dedup by first occurrence, ds_add_f32 into
// a [128][128] LDS accumulator (bank pattern 2-way = free), then one global
// atomic flush per LDS word.
#define HBLK 250
#define HPER 80
__global__ __launch_bounds__(256) void k_hyper(const int* __restrict__ cls,
                                               const float* __restrict__ af2,
                                               float* __restrict__ hyper) {
  __shared__ float acc[128 * 128];
  const int t = threadIdx.x;
  for (int i = t; i < 128 * 128; i += 256) acc[i] = 0.f;
  __syncthreads();
  const int j0 = blockIdx.x * HPER;
  const int j1 = j0 + HPER;  // NN == HBLK*HPER exactly
  const int d = t & 127;
  const int half = t >> 7;  // 0: slots {0,2}; 1: slots {1,3}
  // prefetch first row + classes
  float v = af2[(long)j0 * 128 + d];
  int c0 = cls[j0], c1 = cls[NN + j0], c2 = cls[2 * NN + j0], c3 = cls[3 * NN + j0];
  for (int j = j0; j < j1; ++j) {
    float vn = 0.f;
    int n0 = 0, n1 = 0, n2 = 0, n3 = 0;
    if (j + 1 < j1) {
      vn = af2[(long)(j + 1) * 128 + d];
      n0 = cls[j + 1];
      n1 = cls[NN + j + 1];
      n2 = cls[2 * NN + j + 1];
      n3 = cls[3 * NN + j + 1];
    }
    if (half == 0) {
      atomicAdd(&acc[c0 * 128 + d], v);  // slot 0 always first occurrence
      if (c2 != c0 && c2 != c1) atomicAdd(&acc[c2 * 128 + d], v);
    } else {
      if (c1 != c0) atomicAdd(&acc[c1 * 128 + d], v);
      if (c3 != c0 && c3 != c1 && c3 != c2) atomicAdd(&acc[c3 * 128 + d], v);
    }
    v = vn;
    c0 = n0;
    c1 = n1;
    c2 = n2;
    c3 = n3;
  }
  __syncthreads();
  for (int i = t; i < 128 * 128; i += 256) {
    float x = acc[i];
    if (x != 0.f) atomAddF(&hyper[i], x);
  }
}

// ---------------------------------------------------------------------------
extern "C" void kernel_launch(void* const* d_in, const int* in_sizes, int n_in,
                              void* d_out, int out_size, void* d_ws, size_t ws_size,
                              hipStream_t stream) {
  (void)in_sizes;
  (void)n_in;
  (void)out_size;
  (void)ws_size;
  const int* ei = (const int*)d_in[0];
  const float* feat = (const float*)d_in[1];
  const float* lin_W = (const float*)d_in[2];
  const float* lin_b = (const float*)d_in[3];
  const float* g1W = (const float*)d_in[4];
  const float* g1b = (const float*)d_in[5];
  const float* g2W = (const float*)d_in[6];
  const float* g2b = (const float*)d_in[7];
  const float* l1W = (const float*)d_in[8];
  const float* l1b = (const float*)d_in[9];

  float* out = (float*)d_out;
  float* H = out;
  float* hyper = out + (size_t)NN * 128;
  float* dots = hyper + 128 * 128;

  float* ws = (float*)d_ws;
  float* A = ws;                          // all_features [(T+1)*NN, 128]
  float* Cb = A + (size_t)NTOT * 128;     // h1 / af2 buffer
  float* Bb = dots;                       // xw / logits buffer aliased onto dots
                                          // (dots is written only by the final
                                          //  GEMM, after the last read of Bb)
  float* dinv = Cb + (size_t)NTOT * 128;  // deg -> dinv [NTOT]
  float* nf = dinv + NTOT;                // feature norms [NN]
  float* nt0 = nf + NN;                   // transformed0 norms [NN]
  int* bn = (int*)(nt0 + NN);             // best_nodes [NE]
  int* cls = bn + NE;                     // classes [NTOT]
  int* hist = cls + NTOT;                 // [128*5]
  float* table = (float*)(hist + 640);    // [128*5]

  const float kScale = 0.08838834764831843f;  // 128^-0.5

  // 1. all_features rows [0,NN) = features
  k_copy_feat<<<(NN * 128 / 4 + 255) / 256, 256, 0, stream>>>(feat, A, NN * 128 / 4);
  // 2. transformed: per-replica linears -> rows [NN, 4*NN)
  gemm128<0, 0><<<dim3(313, 3), 256, 0, stream>>>(feat, lin_W, lin_b, A + (size_t)NN * 128,
                                                  NN, 1.f, 128 * 128, 128,
                                                  (long)NN * 128);
  // 3. row norms
  k_norms<<<10000, 256, 0, stream>>>(feat, A, nf, nt0);
  // 4. degree init (self loops + structured extra edges)
  k_deg_init<<<(NTOT + 255) / 256, 256, 0, stream>>>(dinv);
  // 5. cosine-sim replica pick + degree atomics
  k_sim<<<NE / 4, 256, 0, stream>>>(ei, feat, A, nf, nt0, bn, dinv);
  // 6. deg -> 1/sqrt(deg)
  k_dinv<<<(NTOT + 255) / 256, 256, 0, stream>>>(dinv);
  // 7. GCN1: xw1 = relu(all_features) @ W1
  gemm128<1, 0><<<dim3(NTOT / 64, 1), 256, 0, stream>>>(A, g1W, nullptr, Bb, NTOT, 1.f,
                                                        0, 0, 0);
  // 8-9. structured init + edge scatter -> h1 (pre-relu) in Cb
  k_gcn_init<<<NTOT / 2, 256, 0, stream>>>(Bb, dinv, g1b, Cb);
  k_scatter<<<NE / 4, 256, 0, stream>>>(ei, bn, Bb, dinv, Cb);
  // 10. GCN2: xw2 = relu(h1) @ W2
  gemm128<1, 0><<<dim3(NTOT / 64, 1), 256, 0, stream>>>(Cb, g2W, nullptr, Bb, NTOT, 1.f,
                                                        0, 0, 0);
  // 11-12. structured init + edge scatter -> af2 in Cb
  k_gcn_init<<<NTOT / 2, 256, 0, stream>>>(Bb, dinv, g2b, Cb);
  k_scatter<<<NE / 4, 256, 0, stream>>>(ei, bn, Bb, dinv, Cb);
  // 13. logits = relu(af2) @ lin1_W + lin1_b -> Bb
  gemm128<1, 0><<<dim3(NTOT / 64, 1), 256, 0, stream>>>(Cb, l1W, l1b, Bb, NTOT, 1.f, 0,
                                                        0, 0);
  // 14. per-row argmax -> classes
  k_argmax<<<NTOT / 2, 256, 0, stream>>>(Bb, cls);
  // 15. zero hyper + hist
  k_zero_small<<<64, 256, 0, stream>>>(hyper, hist);
  // 16-17. vote histogram -> per-class softmax table
  k_hist<<<(NN + 255) / 256, 256, 0, stream>>>(cls, hist);
  k_table<<<1, 128, 0, stream>>>(hist, table);
  // 18. H output (softmax over nodes, via count table)
  k_hwrite<<<NN / 2, 256, 0, stream>>>(cls, table, H);
  // 19. hyperedge features (LDS-accumulated)
  k_hyper<<<HBLK, 256, 0, stream>>>(cls, Cb, hyper);
  // 20. dots = all_features @ hyper^T * scale
  gemm128<0, 1><<<dim3(NTOT / 64, 1), 256, 0, stream>>>(A, hyper, nullptr, dots, NTOT,
                                                        kScale, 0, 0, 0);
}

// Round 4
// 740.190 us; speedup vs baseline: 2.3213x; 1.2281x over previous
//
#include <hip/hip_runtime.h>
#include <math.h>

#define NN 20000
#define NE 160000
#define TT 3
#define DD 128
#define NTOT 80000   // (TT+1)*NN
#define N3 60000     // TT*NN

__device__ __forceinline__ float waveReduceSum(float v) {
#pragma unroll
  for (int off = 32; off >= 1; off >>= 1)
    v += __shfl_xor(v, off, 64);
  return v;
}

__device__ __forceinline__ void atomAddF(float* p, float v) {
  unsafeAtomicAdd(p, v);
}

// ---------------------------------------------------------------------------
// copy features into all_features rows [0, NN)
__global__ __launch_bounds__(256) void k_copy_feat(const float* __restrict__ src,
                                                   float* __restrict__ dst, int n4) {
  int i = blockIdx.x * 256 + threadIdx.x;
  if (i < n4) ((float4*)dst)[i] = ((const float4*)src)[i];
}

// ---------------------------------------------------------------------------
// Generic [M,128] @ [128,128] GEMM. W (optionally transposed) staged in LDS,
// X tile staged transposed in LDS. 64 rows x 128 cols per block, 8x4 per thread.
// DO_ARGMAX: instead of storing the output tile, compute per-row argmax
// (first-max tie-break) via half-wave shuffle reduce and write cls[row].
template <int RELU_IN, int TRANS_W, int DO_ARGMAX>
__global__ __launch_bounds__(256) void gemm128(const float* __restrict__ X,
                                               const float* __restrict__ W,
                                               const float* __restrict__ bias,
                                               float* __restrict__ out, int M,
                                               float scale, int wStride, int bStride,
                                               long oStride, int* __restrict__ cls) {
  __shared__ float Ws[64 * 132];
  __shared__ float Xs[64 * 68];
  const int tid = threadIdx.x;
  const int rbase = blockIdx.x * 64;
  W += (long)blockIdx.y * wStride;
  if (bias) bias += (long)blockIdx.y * bStride;
  out += (long)blockIdx.y * oStride;

  const int c0 = (tid & 31) * 4;
  const int r0 = (tid >> 5) * 8;
  float acc[8][4];
#pragma unroll
  for (int i = 0; i < 8; ++i)
#pragma unroll
    for (int j = 0; j < 4; ++j) acc[i][j] = 0.f;

  for (int kt = 0; kt < 128; kt += 64) {
    __syncthreads();
    if (!TRANS_W) {
      for (int i = tid; i < 64 * 128; i += 256) {
        int kl = i >> 7, c = i & 127;
        Ws[kl * 132 + c] = W[(kt + kl) * 128 + c];
      }
    } else {
      for (int i = tid; i < 64 * 128; i += 256) {
        int kl = i & 63, c = i >> 6;
        Ws[kl * 132 + c] = W[c * 128 + kt + kl];
      }
    }
    for (int i = tid; i < 64 * 64; i += 256) {
      int kl = i & 63, row = i >> 6;
      int gr = rbase + row;
      float x = (gr < M) ? X[(long)gr * 128 + kt + kl] : 0.f;
      if (RELU_IN) x = fmaxf(x, 0.f);
      Xs[kl * 68 + row] = x;
    }
    __syncthreads();
#pragma unroll 8
    for (int kl = 0; kl < 64; ++kl) {
      const float4 b4 = *(const float4*)&Ws[kl * 132 + c0];
      const float4 a04 = *(const float4*)&Xs[kl * 68 + r0];
      const float4 a14 = *(const float4*)&Xs[kl * 68 + r0 + 4];
      float a[8] = {a04.x, a04.y, a04.z, a04.w, a14.x, a14.y, a14.z, a14.w};
      float b[4] = {b4.x, b4.y, b4.z, b4.w};
#pragma unroll
      for (int i = 0; i < 8; ++i)
#pragma unroll
        for (int j = 0; j < 4; ++j) acc[i][j] = fmaf(a[i], b[j], acc[i][j]);
    }
  }
  float bb0 = 0.f, bb1 = 0.f, bb2 = 0.f, bb3 = 0.f;
  if (bias) {
    bb0 = bias[c0];
    bb1 = bias[c0 + 1];
    bb2 = bias[c0 + 2];
    bb3 = bias[c0 + 3];
  }
  if (DO_ARGMAX) {
#pragma unroll
    for (int i = 0; i < 8; ++i) {
      float v0 = acc[i][0] * scale + bb0;
      float v1 = acc[i][1] * scale + bb1;
      float v2 = acc[i][2] * scale + bb2;
      float v3 = acc[i][3] * scale + bb3;
      float bv = v0;
      int bc = c0;
      if (v1 > bv) { bv = v1; bc = c0 + 1; }
      if (v2 > bv) { bv = v2; bc = c0 + 2; }
      if (v3 > bv) { bv = v3; bc = c0 + 3; }
#pragma unroll
      for (int off = 16; off >= 1; off >>= 1) {
        float ov = __shfl_xor(bv, off, 64);
        int oc = __shfl_xor(bc, off, 64);
        if (ov > bv || (ov == bv && oc < bc)) {
          bv = ov;
          bc = oc;
        }
      }
      int gr = rbase + r0 + i;
      if ((tid & 31) == 0 && gr < M) cls[gr] = bc;
    }
  } else {
#pragma unroll
    for (int i = 0; i < 8; ++i) {
      int gr = rbase + r0 + i;
      if (gr < M) {
        float4 v;
        v.x = acc[i][0] * scale + bb0;
        v.y = acc[i][1] * scale + bb1;
        v.z = acc[i][2] * scale + bb2;
        v.w = acc[i][3] * scale + bb3;
        *(float4*)&out[(long)gr * 128 + c0] = v;
      }
    }
  }
}

// ---------------------------------------------------------------------------
// row norms: first NN waves -> ||features[j]||, next NN -> ||transformed0[j]||
__global__ __launch_bounds__(256) void k_norms(const float* __restrict__ feat,
                                               const float* __restrict__ A,
                                               float* __restrict__ nf,
                                               float* __restrict__ nt0) {
  int w = blockIdx.x * 4 + (threadIdx.x >> 6);
  int lane = threadIdx.x & 63;
  if (w >= 2 * NN) return;
  const float* p = (w < NN) ? (feat + (long)w * 128) : (A + (long)(NN + (w - NN)) * 128);
  float v0 = p[lane], v1 = p[lane + 64];
  float s = waveReduceSum(v0 * v0 + v1 * v1);
  if (lane == 0) {
    float r = sqrtf(s);
    if (w < NN) nf[w] = r;
    else nt0[w - NN] = r;
  }
}

__global__ __launch_bounds__(256) void k_deg_init(float* __restrict__ deg) {
  int v = blockIdx.x * 256 + threadIdx.x;
  if (v < NTOT) deg[v] = (v < N3) ? 2.f : 1.f;
}

// cosine-sim replica selection; one wave per edge. Also deg atomics for the
// two data-dependent edge families.
__global__ __launch_bounds__(256) void k_sim(const int* __restrict__ ei,
                                             const float* __restrict__ feat,
                                             const float* __restrict__ A,
                                             const float* __restrict__ nf,
                                             const float* __restrict__ nt0,
                                             int* __restrict__ bn,
                                             float* __restrict__ deg) {
  int e = blockIdx.x * 4 + (threadIdx.x >> 6);
  int lane = threadIdx.x & 63;
  if (e >= NE) return;
  int s = ei[e];
  const float* fp = feat + (long)s * 128;
  float a0 = fp[lane], a1 = fp[lane + 64];
  float na = nf[s];
  float bv = 0.f;
  int bk = 0;
#pragma unroll
  for (int k = 0; k < 3; ++k) {
    int j = 3 * e + k;
    if (j >= NE) j -= NE;
    if (j >= NE) j -= NE;
    int d = ei[NE + j];
    const float* bp = A + (long)(NN + d) * 128;
    float dot = waveReduceSum(a0 * bp[lane] + a1 * bp[lane + 64]);
    float sim = dot / fmaxf(na * nt0[d], 1e-8f);
    if (k == 0 || sim > bv) {
      bv = sim;
      bk = k;
    }
  }
  if (lane == 0) {
    int d0 = ei[NE + e];
    int b2 = d0 + bk * NN;
    bn[e] = b2;
    atomAddF(&deg[d0], 1.f);
    atomAddF(&deg[b2], 1.f);
  }
}

__global__ __launch_bounds__(256) void k_dinv(float* __restrict__ deg) {
  int v = blockIdx.x * 256 + threadIdx.x;
  if (v < NTOT) deg[v] = 1.f / sqrtf(deg[v]);
}

// structured GCN contributions: self-loop + extra edges, plus bias
__global__ __launch_bounds__(256) void k_gcn_init(const float* __restrict__ xw,
                                                  const float* __restrict__ dinv,
                                                  const float* __restrict__ bias,
                                                  float* __restrict__ out) {
  int v = blockIdx.x * 2 + (threadIdx.x >> 7);
  int c = threadIdx.x & 127;
  if (v >= NTOT) return;
  float dv = dinv[v];
  float acc = bias[c] + dv * dv * xw[(long)v * 128 + c];
  if (v < NN) {
    acc += dv * dv * xw[(long)v * 128 + c];  // extra edge (j, j)
  } else if (v < N3) {
    int j = (v < 2 * NN) ? (v - NN) : (v - 2 * NN);
    acc += dinv[j] * dv * xw[(long)j * 128 + c];  // extra edge (j, i*NN + j)
  }
  out[(long)v * 128 + c] = acc;
}

// unstructured edges: (src, dst) and (src, best_node); one wave per edge
__global__ __launch_bounds__(256) void k_scatter(const int* __restrict__ ei,
                                                 const int* __restrict__ bn,
                                                 const float* __restrict__ xw,
                                                 const float* __restrict__ dinv,
                                                 float* __restrict__ out) {
  int e = blockIdx.x * 4 + (threadIdx.x >> 6);
  int lane = threadIdx.x & 63;
  if (e >= NE) return;
  int s = ei[e], d1 = ei[NE + e], d2 = bn[e];
  float ds = dinv[s];
  float w1 = ds * dinv[d1], w2 = ds * dinv[d2];
  const float* xr = xw + (long)s * 128;
  float x0 = xr[lane], x1 = xr[lane + 64];
  atomAddF(&out[(long)d1 * 128 + lane], w1 * x0);
  atomAddF(&out[(long)d1 * 128 + lane + 64], w1 * x1);
  atomAddF(&out[(long)d2 * 128 + lane], w2 * x0);
  atomAddF(&out[(long)d2 * 128 + lane + 64], w2 * x1);
}

__global__ __launch_bounds__(256) void k_zero_small(float* __restrict__ hyper,
                                                    int* __restrict__ hist) {
  int i = blockIdx.x * 256 + threadIdx.x;
  if (i < 128 * 128) hyper[i] = 0.f;
  if (i < 640) hist[i] = 0;
}

// vote histogram: hist[c][m] = #nodes whose count for class c is exactly m.
// LDS-accumulated per block (20 blocks x 1000 nodes), one flush per block.
#define HISTBLK 20
__global__ __launch_bounds__(256) void k_hist(const int* __restrict__ cls,
                                              int* __restrict__ hist) {
  __shared__ int sh[640];
  const int t = threadIdx.x;
  for (int i = t; i < 640; i += 256) sh[i] = 0;
  __syncthreads();
  const int per = NN / HISTBLK;  // 1000
  const int j0 = blockIdx.x * per;
  for (int j = j0 + t; j < j0 + per; j += 256) {
    int cc[4] = {cls[j], cls[NN + j], cls[2 * NN + j], cls[3 * NN + j]};
#pragma unroll
    for (int i = 0; i < 4; ++i) {
      bool first = true;
      int m = 0;
#pragma unroll
      for (int k = 0; k < 4; ++k) {
        if (cc[k] == cc[i]) {
          if (k < i) first = false;
          m++;
        }
      }
      if (first) atomicAdd(&sh[cc[i] * 5 + m], 1);
    }
  }
  __syncthreads();
  for (int i = t; i < 640; i += 256) {
    int v = sh[i];
    if (v) atomicAdd(&hist[i], v);
  }
}

// per-class softmax table over count values 0..4
__global__ void k_table(const int* __restrict__ hist, float* __restrict__ table) {
  int c = threadIdx.x;
  if (c >= 128) return;
  int cnt[5];
  int tot = 0;
  for (int v = 1; v <= 4; ++v) {
    cnt[v] = hist[c * 5 + v];
    tot += cnt[v];
  }
  cnt[0] = NN - tot;
  int m = 0;
  for (int v = 0; v <= 4; ++v)
    if (cnt[v] > 0) m = v;
  float ex[5];
  float denom = 0.f;
  for (int v = 0; v <= 4; ++v) {
    ex[v] = expf((float)(v - m));
    denom += (float)cnt[v] * ex[v];
  }
  for (int v = 0; v <= 4; ++v) table[c * 5 + v] = ex[v] / denom;
}

__global__ __launch_bounds__(256) void k_hwrite(const int* __restrict__ cls,
                                                const float* __restrict__ table,
                                                float* __restrict__ H) {
  int j = blockIdx.x * 2 + (threadIdx.x >> 7);
  int c = threadIdx.x & 127;
  if (j >= NN) return;
  int c0 = cls[j], c1 = cls[NN + j], c2 = cls[2 * NN + j], c3 = cls[3 * NN + j];
  int cnt = (c == c0) + (c == c1) + (c == c2) + (c == c3);
  H[(long)j * 128 + c] = table[c * 5 + cnt];
}

// ---------------------------------------------------------------------------
// hyper[c][d] = sum over nodes voting for class c of af2[j][d].
// LDS-accumulated: 250 blocks x 80 nodes; per node, 256 threads cover
// 2 class-slots x 128 dims each, dedup by first occurrence, ds_add_f32 into
// a [128][128] LDS accumulator, then one global atomic flush per LDS word.
#define HBLK 250
#define HPER 80
__global__ __launch_bounds__(256) void k_hyper(const int* __restrict__ cls,
                                               const float* __restrict__ af2,
                                               float* __restrict__ hyper) {
  __shared__ float acc[128 * 128];
  const int t = threadIdx.x;
  for (int i = t; i < 128 * 128; i += 256) acc[i] = 0.f;
  __syncthreads();
  const int j0 = blockIdx.x * HPER;
  const int j1 = j0 + HPER;  // NN == HBLK*HPER exactly
  const int d = t & 127;
  const int half = t >> 7;  // 0: slots {0,2}; 1: slots {1,3}
  // prefetch first row + classes
  float v = af2[(long)j0 * 128 + d];
  int c0 = cls[j0], c1 = cls[NN + j0], c2 = cls[2 * NN + j0], c3 = cls[3 * NN + j0];
  for (int j = j0; j < j1; ++j) {
    float vn = 0.f;
    int n0 = 0, n1 = 0, n2 = 0, n3 = 0;
    if (j + 1 < j1) {
      vn = af2[(long)(j + 1) * 128 + d];
      n0 = cls[j + 1];
      n1 = cls[NN + j + 1];
      n2 = cls[2 * NN + j + 1];
      n3 = cls[3 * NN + j + 1];
    }
    if (half == 0) {
      atomicAdd(&acc[c0 * 128 + d], v);  // slot 0 always first occurrence
      if (c2 != c0 && c2 != c1) atomicAdd(&acc[c2 * 128 + d], v);
    } else {
      if (c1 != c0) atomicAdd(&acc[c1 * 128 + d], v);
      if (c3 != c0 && c3 != c1 && c3 != c2) atomicAdd(&acc[c3 * 128 + d], v);
    }
    v = vn;
    c0 = n0;
    c1 = n1;
    c2 = n2;
    c3 = n3;
  }
  __syncthreads();
  for (int i = t; i < 128 * 128; i += 256) {
    float x = acc[i];
    if (x != 0.f) atomAddF(&hyper[i], x);
  }
}

// ---------------------------------------------------------------------------
extern "C" void kernel_launch(void* const* d_in, const int* in_sizes, int n_in,
                              void* d_out, int out_size, void* d_ws, size_t ws_size,
                              hipStream_t stream) {
  (void)in_sizes;
  (void)n_in;
  (void)out_size;
  (void)ws_size;
  const int* ei = (const int*)d_in[0];
  const float* feat = (const float*)d_in[1];
  const float* lin_W = (const float*)d_in[2];
  const float* lin_b = (const float*)d_in[3];
  const float* g1W = (const float*)d_in[4];
  const float* g1b = (const float*)d_in[5];
  const float* g2W = (const float*)d_in[6];
  const float* g2b = (const float*)d_in[7];
  const float* l1W = (const float*)d_in[8];
  const float* l1b = (const float*)d_in[9];

  float* out = (float*)d_out;
  float* H = out;
  float* hyper = out + (size_t)NN * 128;
  float* dots = hyper + 128 * 128;

  float* ws = (float*)d_ws;
  float* A = ws;                          // all_features [(T+1)*NN, 128]
  float* Cb = A + (size_t)NTOT * 128;     // h1 / af2 buffer
  float* Bb = dots;                       // xw buffer aliased onto dots
                                          // (dots is written only by the final
                                          //  GEMM, after the last read of Bb)
  float* dinv = Cb + (size_t)NTOT * 128;  // deg -> dinv [NTOT]
  float* nf = dinv + NTOT;                // feature norms [NN]
  float* nt0 = nf + NN;                   // transformed0 norms [NN]
  int* bn = (int*)(nt0 + NN);             // best_nodes [NE]
  int* cls = bn + NE;                     // classes [NTOT]
  int* hist = cls + NTOT;                 // [128*5]
  float* table = (float*)(hist + 640);    // [128*5]

  const float kScale = 0.08838834764831843f;  // 128^-0.5

  // 1. all_features rows [0,NN) = features
  k_copy_feat<<<(NN * 128 / 4 + 255) / 256, 256, 0, stream>>>(feat, A, NN * 128 / 4);
  // 2. transformed: per-replica linears -> rows [NN, 4*NN)
  gemm128<0, 0, 0><<<dim3(313, 3), 256, 0, stream>>>(
      feat, lin_W, lin_b, A + (size_t)NN * 128, NN, 1.f, 128 * 128, 128,
      (long)NN * 128, nullptr);
  // 3. row norms
  k_norms<<<10000, 256, 0, stream>>>(feat, A, nf, nt0);
  // 4. degree init (self loops + structured extra edges)
  k_deg_init<<<(NTOT + 255) / 256, 256, 0, stream>>>(dinv);
  // 5. cosine-sim replica pick + degree atomics
  k_sim<<<NE / 4, 256, 0, stream>>>(ei, feat, A, nf, nt0, bn, dinv);
  // 6. deg -> 1/sqrt(deg)
  k_dinv<<<(NTOT + 255) / 256, 256, 0, stream>>>(dinv);
  // 7. GCN1: xw1 = relu(all_features) @ W1
  gemm128<1, 0, 0><<<dim3(NTOT / 64, 1), 256, 0, stream>>>(A, g1W, nullptr, Bb, NTOT,
                                                           1.f, 0, 0, 0, nullptr);
  // 8-9. structured init + edge scatter -> h1 (pre-relu) in Cb
  k_gcn_init<<<NTOT / 2, 256, 0, stream>>>(Bb, dinv, g1b, Cb);
  k_scatter<<<NE / 4, 256, 0, stream>>>(ei, bn, Bb, dinv, Cb);
  // 10. GCN2: xw2 = relu(h1) @ W2
  gemm128<1, 0, 0><<<dim3(NTOT / 64, 1), 256, 0, stream>>>(Cb, g2W, nullptr, Bb, NTOT,
                                                           1.f, 0, 0, 0, nullptr);
  // 11-12. structured init + edge scatter -> af2 in Cb
  k_gcn_init<<<NTOT / 2, 256, 0, stream>>>(Bb, dinv, g2b, Cb);
  k_scatter<<<NE / 4, 256, 0, stream>>>(ei, bn, Bb, dinv, Cb);
  // 13+14. logits GEMM with fused per-row argmax -> classes (no logits store)
  gemm128<1, 0, 1><<<dim3(NTOT / 64, 1), 256, 0, stream>>>(Cb, l1W, l1b, nullptr, NTOT,
                                                           1.f, 0, 0, 0, cls);
  // 15. zero hyper + hist
  k_zero_small<<<64, 256, 0, stream>>>(hyper, hist);
  // 16-17. vote histogram (LDS) -> per-class softmax table
  k_hist<<<HISTBLK, 256, 0, stream>>>(cls, hist);
  k_table<<<1, 128, 0, stream>>>(hist, table);
  // 18. H output (softmax over nodes, via count table)
  k_hwrite<<<NN / 2, 256, 0, stream>>>(cls, table, H);
  // 19. hyperedge features (LDS-accumulated)
  k_hyper<<<HBLK, 256, 0, stream>>>(cls, Cb, hyper);
  // 20. dots = all_features @ hyper^T * scale
  gemm128<0, 1, 0><<<dim3(NTOT / 64, 1), 256, 0, stream>>>(A, hyper, nullptr, dots,
                                                           NTOT, kScale, 0, 0, 0,
                                                           nullptr);
}

// Round 6
// 560.573 us; speedup vs baseline: 3.0651x; 1.3204x over previous
//
#include <hip/hip_runtime.h>
#include <math.h>

#define NN 20000
#define NE 160000
#define TT 3
#define DD 128
#define NTOT 80000   // (TT+1)*NN
#define N3 60000     // TT*NN
#define NBLK1 79     // ceil(NTOT/1024) for the scan

__device__ __forceinline__ float waveReduceSum(float v) {
#pragma unroll
  for (int off = 32; off >= 1; off >>= 1)
    v += __shfl_xor(v, off, 64);
  return v;
}

__device__ __forceinline__ void atomAddF(float* p, float v) {
  unsafeAtomicAdd(p, v);
}

// ---------------------------------------------------------------------------
// copy features into all_features rows [0, NN)
__global__ __launch_bounds__(256) void k_copy_feat(const float* __restrict__ src,
                                                   float* __restrict__ dst, int n4) {
  int i = blockIdx.x * 256 + threadIdx.x;
  if (i < n4) ((float4*)dst)[i] = ((const float4*)src)[i];
}

// ---------------------------------------------------------------------------
// Generic [M,128] @ [128,128] GEMM. W (optionally transposed) staged in LDS,
// X tile staged transposed in LDS. 64 rows x 128 cols per block, 8x4 per thread.
// DO_ARGMAX: instead of storing the output tile, compute per-row argmax
// (first-max tie-break) via half-wave shuffle reduce and write cls[row].
template <int RELU_IN, int TRANS_W, int DO_ARGMAX>
__global__ __launch_bounds__(256) void gemm128(const float* __restrict__ X,
                                               const float* __restrict__ W,
                                               const float* __restrict__ bias,
                                               float* __restrict__ out, int M,
                                               float scale, int wStride, int bStride,
                                               long oStride, int* __restrict__ cls) {
  __shared__ float Ws[64 * 132];
  __shared__ float Xs[64 * 68];
  const int tid = threadIdx.x;
  const int rbase = blockIdx.x * 64;
  W += (long)blockIdx.y * wStride;
  if (bias) bias += (long)blockIdx.y * bStride;
  out += (long)blockIdx.y * oStride;

  const int c0 = (tid & 31) * 4;
  const int r0 = (tid >> 5) * 8;
  float acc[8][4];
#pragma unroll
  for (int i = 0; i < 8; ++i)
#pragma unroll
    for (int j = 0; j < 4; ++j) acc[i][j] = 0.f;

  for (int kt = 0; kt < 128; kt += 64) {
    __syncthreads();
    if (!TRANS_W) {
      for (int i = tid; i < 64 * 128; i += 256) {
        int kl = i >> 7, c = i & 127;
        Ws[kl * 132 + c] = W[(kt + kl) * 128 + c];
      }
    } else {
      for (int i = tid; i < 64 * 128; i += 256) {
        int kl = i & 63, c = i >> 6;
        Ws[kl * 132 + c] = W[c * 128 + kt + kl];
      }
    }
    for (int i = tid; i < 64 * 64; i += 256) {
      int kl = i & 63, row = i >> 6;
      int gr = rbase + row;
      float x = (gr < M) ? X[(long)gr * 128 + kt + kl] : 0.f;
      if (RELU_IN) x = fmaxf(x, 0.f);
      Xs[kl * 68 + row] = x;
    }
    __syncthreads();
#pragma unroll 8
    for (int kl = 0; kl < 64; ++kl) {
      const float4 b4 = *(const float4*)&Ws[kl * 132 + c0];
      const float4 a04 = *(const float4*)&Xs[kl * 68 + r0];
      const float4 a14 = *(const float4*)&Xs[kl * 68 + r0 + 4];
      float a[8] = {a04.x, a04.y, a04.z, a04.w, a14.x, a14.y, a14.z, a14.w};
      float b[4] = {b4.x, b4.y, b4.z, b4.w};
#pragma unroll
      for (int i = 0; i < 8; ++i)
#pragma unroll
        for (int j = 0; j < 4; ++j) acc[i][j] = fmaf(a[i], b[j], acc[i][j]);
    }
  }
  float bb0 = 0.f, bb1 = 0.f, bb2 = 0.f, bb3 = 0.f;
  if (bias) {
    bb0 = bias[c0];
    bb1 = bias[c0 + 1];
    bb2 = bias[c0 + 2];
    bb3 = bias[c0 + 3];
  }
  if (DO_ARGMAX) {
#pragma unroll
    for (int i = 0; i < 8; ++i) {
      float v0 = acc[i][0] * scale + bb0;
      float v1 = acc[i][1] * scale + bb1;
      float v2 = acc[i][2] * scale + bb2;
      float v3 = acc[i][3] * scale + bb3;
      float bv = v0;
      int bc = c0;
      if (v1 > bv) { bv = v1; bc = c0 + 1; }
      if (v2 > bv) { bv = v2; bc = c0 + 2; }
      if (v3 > bv) { bv = v3; bc = c0 + 3; }
#pragma unroll
      for (int off = 16; off >= 1; off >>= 1) {
        float ov = __shfl_xor(bv, off, 64);
        int oc = __shfl_xor(bc, off, 64);
        if (ov > bv || (ov == bv && oc < bc)) {
          bv = ov;
          bc = oc;
        }
      }
      int gr = rbase + r0 + i;
      if ((tid & 31) == 0 && gr < M) cls[gr] = bc;
    }
  } else {
#pragma unroll
    for (int i = 0; i < 8; ++i) {
      int gr = rbase + r0 + i;
      if (gr < M) {
        float4 v;
        v.x = acc[i][0] * scale + bb0;
        v.y = acc[i][1] * scale + bb1;
        v.z = acc[i][2] * scale + bb2;
        v.w = acc[i][3] * scale + bb3;
        *(float4*)&out[(long)gr * 128 + c0] = v;
      }
    }
  }
}

// ---------------------------------------------------------------------------
// row norms: first NN waves -> ||features[j]||, next NN -> ||transformed0[j]||
__global__ __launch_bounds__(256) void k_norms(const float* __restrict__ feat,
                                               const float* __restrict__ A,
                                               float* __restrict__ nf,
                                               float* __restrict__ nt0) {
  int w = blockIdx.x * 4 + (threadIdx.x >> 6);
  int lane = threadIdx.x & 63;
  if (w >= 2 * NN) return;
  const float* p = (w < NN) ? (feat + (long)w * 128) : (A + (long)(NN + (w - NN)) * 128);
  float v0 = p[lane], v1 = p[lane + 64];
  float s = waveReduceSum(v0 * v0 + v1 * v1);
  if (lane == 0) {
    float r = sqrtf(s);
    if (w < NN) nf[w] = r;
    else nt0[w - NN] = r;
  }
}

// cosine-sim replica selection; one wave per edge (no more deg atomics —
// degrees come from the CSR histogram).
__global__ __launch_bounds__(256) void k_sim(const int* __restrict__ ei,
                                             const float* __restrict__ feat,
                                             const float* __restrict__ A,
                                             const float* __restrict__ nf,
                                             const float* __restrict__ nt0,
                                             int* __restrict__ bn) {
  int e = blockIdx.x * 4 + (threadIdx.x >> 6);
  int lane = threadIdx.x & 63;
  if (e >= NE) return;
  int s = ei[e];
  const float* fp = feat + (long)s * 128;
  float a0 = fp[lane], a1 = fp[lane + 64];
  float na = nf[s];
  float bv = 0.f;
  int bk = 0;
#pragma unroll
  for (int k = 0; k < 3; ++k) {
    int j = 3 * e + k;
    if (j >= NE) j -= NE;
    if (j >= NE) j -= NE;
    int d = ei[NE + j];
    const float* bp = A + (long)(NN + d) * 128;
    float dot = waveReduceSum(a0 * bp[lane] + a1 * bp[lane + 64]);
    float sim = dot / fmaxf(na * nt0[d], 1e-8f);
    if (k == 0 || sim > bv) {
      bv = sim;
      bk = k;
    }
  }
  if (lane == 0) bn[e] = ei[NE + e] + bk * NN;
}

// ---------------------------------------------------------------------------
// CSR build: count -> scan(3 phases) -> fill. Shared by both GCN layers.
__global__ __launch_bounds__(256) void k_zero_count(int* __restrict__ count) {
  int v = blockIdx.x * 256 + threadIdx.x;
  if (v < NTOT) count[v] = 0;
}

__global__ __launch_bounds__(256) void k_count(const int* __restrict__ ei,
                                               const int* __restrict__ bn,
                                               int* __restrict__ count) {
  int e = blockIdx.x * 256 + threadIdx.x;
  if (e < NE) {
    atomicAdd(&count[ei[NE + e]], 1);
    atomicAdd(&count[bn[e]], 1);
  }
}

// dinv[v] = rsqrt(unstructured_count + structured (2 for v<N3, else 1))
__global__ __launch_bounds__(256) void k_dinv(const int* __restrict__ count,
                                              float* __restrict__ dinv) {
  int v = blockIdx.x * 256 + threadIdx.x;
  if (v < NTOT) {
    float deg = (float)count[v] + ((v < N3) ? 2.f : 1.f);
    dinv[v] = 1.f / sqrtf(deg);
  }
}

// scan phase 1: per-1024-block local exclusive scan + block sums
__global__ __launch_bounds__(256) void k_scan1(const int* __restrict__ count,
                                               int* __restrict__ start,
                                               int* __restrict__ bsum) {
  __shared__ int sh[256];
  const int b = blockIdx.x, t = threadIdx.x;
  const int base = b * 1024 + t * 4;
  int c[4];
  int s = 0;
#pragma unroll
  for (int k = 0; k < 4; ++k) {
    int idx = base + k;
    c[k] = (idx < NTOT) ? count[idx] : 0;
    s += c[k];
  }
  sh[t] = s;
  __syncthreads();
  for (int off = 1; off < 256; off <<= 1) {
    int v = (t >= off) ? sh[t - off] : 0;
    __syncthreads();
    sh[t] += v;
    __syncthreads();
  }
  if (t == 255) bsum[b] = sh[255];
  int run = sh[t] - s;  // exclusive prefix of this thread
#pragma unroll
  for (int k = 0; k < 4; ++k) {
    int idx = base + k;
    if (idx < NTOT) start[idx] = run;
    run += c[k];
  }
}

// scan phase 2: exclusive scan of NBLK1 block sums (single block)
__global__ __launch_bounds__(256) void k_scan2(int* __restrict__ bsum) {
  __shared__ int sh[256];
  const int t = threadIdx.x;
  int v = (t < NBLK1) ? bsum[t] : 0;
  sh[t] = v;
  __syncthreads();
  for (int off = 1; off < 256; off <<= 1) {
    int u = (t >= off) ? sh[t - off] : 0;
    __syncthreads();
    sh[t] += u;
    __syncthreads();
  }
  if (t < NBLK1) bsum[t] = sh[t] - v;
}

// scan phase 3: add block offsets; init cursor = start
__global__ __launch_bounds__(256) void k_scan3(int* __restrict__ start,
                                               const int* __restrict__ bsum,
                                               int* __restrict__ cursor) {
  int i = blockIdx.x * 256 + threadIdx.x;
  if (i < NTOT) {
    int v = start[i] + bsum[i >> 10];
    start[i] = v;
    cursor[i] = v;
  }
}

// fill CSR entries: (src, weight) packed in int2
__global__ __launch_bounds__(256) void k_fill(const int* __restrict__ ei,
                                              const int* __restrict__ bn,
                                              const float* __restrict__ dinv,
                                              int* __restrict__ cursor,
                                              int2* __restrict__ ent) {
  int g = blockIdx.x * 256 + threadIdx.x;
  if (g >= 2 * NE) return;
  int e = (g < NE) ? g : g - NE;
  int s = ei[e];
  int d = (g < NE) ? ei[NE + e] : bn[e];
  float w = dinv[s] * dinv[d];
  int pos = atomicAdd(&cursor[d], 1);
  ent[pos] = make_int2(s, __float_as_int(w));
}

// ---------------------------------------------------------------------------
// Fused GCN aggregate: out[v] = bias + selfloop + extra + sum_{CSR} w*xw[src].
// One wave per row, 2 floats/lane, prefetched entry loop, no atomics.
__global__ __launch_bounds__(256) void k_agg(const int2* __restrict__ ent,
                                             const int* __restrict__ start,
                                             const int* __restrict__ end,
                                             const float* __restrict__ xw,
                                             const float* __restrict__ dinv,
                                             const float* __restrict__ bias,
                                             float* __restrict__ out) {
  int v = blockIdx.x * 4 + (threadIdx.x >> 6);
  int lane = threadIdx.x & 63;
  float dv = dinv[v];
  const float* xr = xw + (long)v * 128;
  float b0 = xr[lane], b1 = xr[lane + 64];
  float acc0 = bias[lane] + dv * dv * b0;
  float acc1 = bias[lane + 64] + dv * dv * b1;
  if (v < NN) {
    acc0 += dv * dv * b0;  // extra edge (j, j)
    acc1 += dv * dv * b1;
  } else if (v < N3) {
    int j = (v < 2 * NN) ? v - NN : v - 2 * NN;
    const float* xj = xw + (long)j * 128;
    float w = dinv[j] * dv;
    acc0 = fmaf(w, xj[lane], acc0);  // extra edge (j, i*NN + j)
    acc1 = fmaf(w, xj[lane + 64], acc1);
  }
  const int i1 = end[v];
  int i = start[v];
  if (i < i1) {
    int2 en = ent[i];
    for (; i < i1; ++i) {
      int2 nx = en;
      if (i + 1 < i1) nx = ent[i + 1];
      float w = __int_as_float(en.y);
      const float* xs = xw + (long)en.x * 128;
      acc0 = fmaf(w, xs[lane], acc0);
      acc1 = fmaf(w, xs[lane + 64], acc1);
      en = nx;
    }
  }
  out[(long)v * 128 + lane] = acc0;
  out[(long)v * 128 + lane + 64] = acc1;
}

__global__ __launch_bounds__(256) void k_zero_small(float* __restrict__ hyper,
                                                    int* __restrict__ hist) {
  int i = blockIdx.x * 256 + threadIdx.x;
  if (i < 128 * 128) hyper[i] = 0.f;
  if (i < 640) hist[i] = 0;
}

// vote histogram: hist[c][m] = #nodes whose count for class c is exactly m.
// LDS-accumulated per block (20 blocks x 1000 nodes), one flush per block.
#define HISTBLK 20
__global__ __launch_bounds__(256) void k_hist(const int* __restrict__ cls,
                                              int* __restrict__ hist) {
  __shared__ int sh[640];
  const int t = threadIdx.x;
  for (int i = t; i < 640; i += 256) sh[i] = 0;
  __syncthreads();
  const int per = NN / HISTBLK;  // 1000
  const int j0 = blockIdx.x * per;
  for (int j = j0 + t; j < j0 + per; j += 256) {
    int cc[4] = {cls[j], cls[NN + j], cls[2 * NN + j], cls[3 * NN + j]};
#pragma unroll
    for (int i = 0; i < 4; ++i) {
      bool first = true;
      int m = 0;
#pragma unroll
      for (int k = 0; k < 4; ++k) {
        if (cc[k] == cc[i]) {
          if (k < i) first = false;
          m++;
        }
      }
      if (first) atomicAdd(&sh[cc[i] * 5 + m], 1);
    }
  }
  __syncthreads();
  for (int i = t; i < 640; i += 256) {
    int v = sh[i];
    if (v) atomicAdd(&hist[i], v);
  }
}

// per-class softmax table over count values 0..4
__global__ void k_table(const int* __restrict__ hist, float* __restrict__ table) {
  int c = threadIdx.x;
  if (c >= 128) return;
  int cnt[5];
  int tot = 0;
  for (int v = 1; v <= 4; ++v) {
    cnt[v] = hist[c * 5 + v];
    tot += cnt[v];
  }
  cnt[0] = NN - tot;
  int m = 0;
  for (int v = 0; v <= 4; ++v)
    if (cnt[v] > 0) m = v;
  float ex[5];
  float denom = 0.f;
  for (int v = 0; v <= 4; ++v) {
    ex[v] = expf((float)(v - m));
    denom += (float)cnt[v] * ex[v];
  }
  for (int v = 0; v <= 4; ++v) table[c * 5 + v] = ex[v] / denom;
}

__global__ __launch_bounds__(256) void k_hwrite(const int* __restrict__ cls,
                                                const float* __restrict__ table,
                                                float* __restrict__ H) {
  int j = blockIdx.x * 2 + (threadIdx.x >> 7);
  int c = threadIdx.x & 127;
  if (j >= NN) return;
  int c0 = cls[j], c1 = cls[NN + j], c2 = cls[2 * NN + j], c3 = cls[3 * NN + j];
  int cnt = (c == c0) + (c == c1) + (c == c2) + (c == c3);
  H[(long)j * 128 + c] = table[c * 5 + cnt];
}

// ---------------------------------------------------------------------------
// hyper[c][d] = sum over nodes voting for class c of af2[j][d].
// LDS-accumulated: 250 blocks x 80 nodes.
#define HBLK 250
#define HPER 80
__global__ __launch_bounds__(256) void k_hyper(const int* __restrict__ cls,
                                               const float* __restrict__ af2,
                                               float* __restrict__ hyper) {
  __shared__ float acc[128 * 128];
  const int t = threadIdx.x;
  for (int i = t; i < 128 * 128; i += 256) acc[i] = 0.f;
  __syncthreads();
  const int j0 = blockIdx.x * HPER;
  const int j1 = j0 + HPER;  // NN == HBLK*HPER exactly
  const int d = t & 127;
  const int half = t >> 7;  // 0: slots {0,2}; 1: slots {1,3}
  float v = af2[(long)j0 * 128 + d];
  int c0 = cls[j0], c1 = cls[NN + j0], c2 = cls[2 * NN + j0], c3 = cls[3 * NN + j0];
  for (int j = j0; j < j1; ++j) {
    float vn = 0.f;
    int n0 = 0, n1 = 0, n2 = 0, n3 = 0;
    if (j + 1 < j1) {
      vn = af2[(long)(j + 1) * 128 + d];
      n0 = cls[j + 1];
      n1 = cls[NN + j + 1];
      n2 = cls[2 * NN + j + 1];
      n3 = cls[3 * NN + j + 1];
    }
    if (half == 0) {
      atomicAdd(&acc[c0 * 128 + d], v);  // slot 0 always first occurrence
      if (c2 != c0 && c2 != c1) atomicAdd(&acc[c2 * 128 + d], v);
    } else {
      if (c1 != c0) atomicAdd(&acc[c1 * 128 + d], v);
      if (c3 != c0 && c3 != c1 && c3 != c2) atomicAdd(&acc[c3 * 128 + d], v);
    }
    v = vn;
    c0 = n0;
    c1 = n1;
    c2 = n2;
    c3 = n3;
  }
  __syncthreads();
  for (int i = t; i < 128 * 128; i += 256) {
    float x = acc[i];
    if (x != 0.f) atomAddF(&hyper[i], x);
  }
}

// ---------------------------------------------------------------------------
extern "C" void kernel_launch(void* const* d_in, const int* in_sizes, int n_in,
                              void* d_out, int out_size, void* d_ws, size_t ws_size,
                              hipStream_t stream) {
  (void)in_sizes;
  (void)n_in;
  (void)out_size;
  (void)ws_size;
  const int* ei = (const int*)d_in[0];
  const float* feat = (const float*)d_in[1];
  const float* lin_W = (const float*)d_in[2];
  const float* lin_b = (const float*)d_in[3];
  const float* g1W = (const float*)d_in[4];
  const float* g1b = (const float*)d_in[5];
  const float* g2W = (const float*)d_in[6];
  const float* g2b = (const float*)d_in[7];
  const float* l1W = (const float*)d_in[8];
  const float* l1b = (const float*)d_in[9];

  float* out = (float*)d_out;
  float* H = out;
  float* hyper = out + (size_t)NN * 128;
  float* dots = hyper + 128 * 128;

  float* ws = (float*)d_ws;
  float* A = ws;                          // all_features [(T+1)*NN, 128]
  float* Cb = A + (size_t)NTOT * 128;     // h1 / af2 buffer
  float* Bb = dots;                       // xw buffer aliased onto dots
                                          // (dots written only by final GEMM)
  float* dinv = Cb + (size_t)NTOT * 128;  // [NTOT]
  float* nf = dinv + NTOT;                // feature norms [NN]
  float* nt0 = nf + NN;                   // transformed0 norms [NN]
  int* bn = (int*)(nt0 + NN);             // best_nodes [NE]
  int* cls = bn + NE;                     // classes [NTOT]
  int* hist = cls + NTOT;                 // [640]
  float* table = (float*)(hist + 640);    // [640]
  int* count = (int*)(table + 640);       // [NTOT]
  int* startA = count + NTOT;             // [NTOT]
  int* cursor = startA + NTOT;            // [NTOT]  (== end after fill)
  int* bsum = cursor + NTOT;              // [128]
  int2* ent = (int2*)(bsum + 128);        // [2*NE] CSR entries (src, weight)

  const float kScale = 0.08838834764831843f;  // 128^-0.5

  // 1. all_features rows [0,NN) = features
  k_copy_feat<<<(NN * 128 / 4 + 255) / 256, 256, 0, stream>>>(feat, A, NN * 128 / 4);
  // 2. transformed: per-replica linears -> rows [NN, 4*NN)
  gemm128<0, 0, 0><<<dim3(313, 3), 256, 0, stream>>>(
      feat, lin_W, lin_b, A + (size_t)NN * 128, NN, 1.f, 128 * 128, 128,
      (long)NN * 128, nullptr);
  // 3. row norms
  k_norms<<<10000, 256, 0, stream>>>(feat, A, nf, nt0);
  // 4. cosine-sim replica pick
  k_zero_count<<<(NTOT + 255) / 256, 256, 0, stream>>>(count);
  k_sim<<<NE / 4, 256, 0, stream>>>(ei, feat, A, nf, nt0, bn);
  // 5. CSR build: count, dinv, scan, fill
  k_count<<<(NE + 255) / 256, 256, 0, stream>>>(ei, bn, count);
  k_dinv<<<(NTOT + 255) / 256, 256, 0, stream>>>(count, dinv);
  k_scan1<<<NBLK1, 256, 0, stream>>>(count, startA, bsum);
  k_scan2<<<1, 256, 0, stream>>>(bsum);
  k_scan3<<<(NTOT + 255) / 256, 256, 0, stream>>>(startA, bsum, cursor);
  k_fill<<<(2 * NE + 255) / 256, 256, 0, stream>>>(ei, bn, dinv, cursor, ent);
  // 6. GCN1: xw1 = relu(all_features) @ W1; fused aggregate -> h1 in Cb
  gemm128<1, 0, 0><<<dim3(NTOT / 64, 1), 256, 0, stream>>>(A, g1W, nullptr, Bb, NTOT,
                                                           1.f, 0, 0, 0, nullptr);
  k_agg<<<NTOT / 4, 256, 0, stream>>>(ent, startA, cursor, Bb, dinv, g1b, Cb);
  // 7. GCN2: xw2 = relu(h1) @ W2; fused aggregate -> af2 in Cb
  gemm128<1, 0, 0><<<dim3(NTOT / 64, 1), 256, 0, stream>>>(Cb, g2W, nullptr, Bb, NTOT,
                                                           1.f, 0, 0, 0, nullptr);
  k_agg<<<NTOT / 4, 256, 0, stream>>>(ent, startA, cursor, Bb, dinv, g2b, Cb);
  // 8. logits GEMM with fused per-row argmax -> classes (no logits store)
  gemm128<1, 0, 1><<<dim3(NTOT / 64, 1), 256, 0, stream>>>(Cb, l1W, l1b, nullptr, NTOT,
                                                           1.f, 0, 0, 0, cls);
  // 9. zero hyper + hist
  k_zero_small<<<64, 256, 0, stream>>>(hyper, hist);
  // 10. vote histogram (LDS) -> per-class softmax table
  k_hist<<<HISTBLK, 256, 0, stream>>>(cls, hist);
  k_table<<<1, 128, 0, stream>>>(hist, table);
  // 11. H output (softmax over nodes, via count table)
  k_hwrite<<<NN / 2, 256, 0, stream>>>(cls, table, H);
  // 12. hyperedge features (LDS-accumulated)
  k_hyper<<<HBLK, 256, 0, stream>>>(cls, Cb, hyper);
  // 13. dots = all_features @ hyper^T * scale
  gemm128<0, 1, 0><<<dim3(NTOT / 64, 1), 256, 0, stream>>>(A, hyper, nullptr, dots,
                                                           NTOT, kScale, 0, 0, 0,
                                                           nullptr);
}